// Round 10
// baseline (644.138 us; speedup 1.0000x reference)
//
#include <hip/hip_runtime.h>
#include <hip/hip_bf16.h>
#include <hip/hip_cooperative_groups.h>
#include <stdint.h>

namespace cg = cooperative_groups;

// Problem constants (from reference)
#define N_NODES 100000
#define N_EDGES 1600000
#define D_NODE  32
#define D_EDGE  16
#define D_HID   64
#define D_OUT   32

// ---------------- workspace layout (bytes) ----------------
#define NFLAGS_OFF  ((size_t)0)         // 2 ints: {is_bf16, is_int64}
#define NB1_OFF     ((size_t)64)        // fp32 [64]
#define NB2_OFF     ((size_t)320)       // fp32 [32]
#define W1BF_OFF    ((size_t)1024)      // bf16 [n=64][k=64] n-major, k>=48 zero
#define W2BF_OFF    ((size_t)9216)      // bf16 [n=32][k=64] n-major
#define COUNTS_OFF  ((size_t)65536)     // int [N_NODES]
#define OFFS_OFF    ((size_t)466944)    // int [N_NODES+1]
#define BLKSUM_OFF  ((size_t)917504)    // int [512]
#define RANK_OFF    ((size_t)1048576)   // int [N_EDGES]
#define MSG_OFF     ((size_t)8388608)   // bf16 message rows, 64 B each

#define SCAN_NB 391   // ceil(100000/256)

typedef __attribute__((ext_vector_type(8))) short bf16x8;
typedef __attribute__((ext_vector_type(4))) float f32x4;

__device__ inline float bf2f(unsigned int u16) {
    return __uint_as_float(u16 << 16);
}
__device__ inline unsigned short f2bf_rne(float f) {
    unsigned int x = __float_as_uint(f);
    unsigned int r = (x + 0x7FFFu + ((x >> 16) & 1u)) >> 16;
    return (unsigned short)r;
}
__device__ inline unsigned int pk_bf2(float a, float b) {
    float2 f; f.x = a; f.y = b;
    __hip_bfloat162 h = __float22bfloat162_rn(f);
    return *reinterpret_cast<unsigned int*>(&h);
}
__device__ inline float ld_f(const void* p, int i, int isbf) {
    if (isbf) return bf2f(((const unsigned short*)p)[i]);
    return ((const float*)p)[i];
}
__device__ inline bf16x8 pack_bf8(float4 v0, float4 v1) {
    union { unsigned int u[4]; bf16x8 v; } r;
    r.u[0] = pk_bf2(v0.x, v0.y);
    r.u[1] = pk_bf2(v0.z, v0.w);
    r.u[2] = pk_bf2(v1.x, v1.y);
    r.u[3] = pk_bf2(v1.z, v1.w);
    return r.v;
}

// ===========================================================================
// MEGA KERNEL: all six phases in ONE cooperative launch (grid.sync between).
// Phase work is byte-identical to the verified r8 pipeline (+ r7's reduce).
// ===========================================================================
__global__ __launch_bounds__(256) void mega_kernel(
        const void* __restrict__ xq, const void* __restrict__ idxq,
        const void* __restrict__ eaq,
        const void* __restrict__ W1q, const void* __restrict__ b1q,
        const void* __restrict__ W2q, const void* __restrict__ b2q,
        char* __restrict__ ws, void* __restrict__ out) {
    cg::grid_group gridg = cg::this_grid();
    const int t = threadIdx.x;
    const int gtid = blockIdx.x * 256 + t;
    const int gthreads = gridDim.x * 256;

    __shared__ __align__(16) unsigned short hbuf[4][16][72];
    __shared__ int sscan[256];
    __shared__ int s_isbf0;

    int* counts = (int*)(ws + COUNTS_OFF);
    int* offs   = (int*)(ws + OFFS_OFF);
    int* blksum = (int*)(ws + BLKSUM_OFF);
    int* rankb  = (int*)(ws + RANK_OFF);
    unsigned short* msg = (unsigned short*)(ws + MSG_OFF);

    // ---- phase 0: init (zero counts; block 0: flags + weights) ----
    for (int i = gtid; i < N_NODES; i += gthreads) counts[i] = 0;
    if (blockIdx.x == 0) {
        if (t < 64) {
            unsigned short u = ((const unsigned short*)xq)[t];
            unsigned long long mb = __ballot(((u >> 7) & 0xFF) >= 140);
            int wodd = ((const int*)idxq)[2 * t + 1];
            unsigned long long mi = __ballot(wodd != 0);
            if (t == 0) {
                int* flags = (int*)(ws + NFLAGS_OFF);
                flags[0] = (mb == 0ULL);
                flags[1] = (mi == 0ULL);
                s_isbf0 = (mb == 0ULL);
            }
        }
        __syncthreads();
        const int isbf0 = s_isbf0;
        float* b1 = (float*)(ws + NB1_OFF);
        float* b2 = (float*)(ws + NB2_OFF);
        unsigned short* w1b = (unsigned short*)(ws + W1BF_OFF);
        unsigned short* w2b = (unsigned short*)(ws + W2BF_OFF);
        if (t < D_HID) b1[t] = ld_f(b1q, t, isbf0);
        if (t < D_OUT) b2[t] = ld_f(b2q, t, isbf0);
        for (int i = t; i < D_HID * 64; i += 256) {
            int n = i >> 6, k = i & 63;
            float v = (k < 48) ? ld_f(W1q, k * D_HID + n, isbf0) : 0.0f;
            w1b[i] = f2bf_rne(v);
        }
        for (int i = t; i < D_OUT * 64; i += 256) {
            int n = i >> 6, k = i & 63;
            w2b[i] = f2bf_rne(ld_f(W2q, k * D_OUT + n, isbf0));
        }
    }
    gridg.sync();

    const int isbf = ((const int*)(ws + NFLAGS_OFF))[0];
    const int is64 = ((const int*)(ws + NFLAGS_OFF))[1];

    // ---- phase 1: histogram + per-edge rank ----
    for (int e = gtid; e < N_EDGES; e += gthreads) {
        int dst;
        if (is64) dst = (int)((const long long*)idxq)[e];
        else      dst = ((const int*)idxq)[e];
        rankb[e] = atomicAdd(counts + dst, 1);
    }
    gridg.sync();

    // ---- phase 2a: chunk-local exclusive scan ----
    for (int c = blockIdx.x; c < SCAN_NB; c += gridDim.x) {
        const int i = c * 256 + t;
        int v = (i < N_NODES) ? counts[i] : 0;
        sscan[t] = v;
        __syncthreads();
        for (int d = 1; d < 256; d <<= 1) {
            int a = (t >= d) ? sscan[t - d] : 0;
            __syncthreads();
            sscan[t] += a;
            __syncthreads();
        }
        if (i < N_NODES) offs[i] = sscan[t] - v;
        if (t == 255) blksum[c] = sscan[255];
        __syncthreads();
    }
    gridg.sync();
    // ---- phase 2b: add chunk prefixes (each chunk sums its blksum prefix) --
    for (int c = blockIdx.x; c < SCAN_NB; c += gridDim.x) {
        int acc = 0;
        for (int j = t; j < c; j += 256) acc += blksum[j];
        sscan[t] = acc;
        __syncthreads();
        for (int d = 128; d > 0; d >>= 1) {
            if (t < d) sscan[t] += sscan[t + d];
            __syncthreads();
        }
        const int prefix = sscan[0];
        const int i = c * 256 + t;
        if (i < N_NODES) offs[i] += prefix;
        __syncthreads();
    }
    if (gtid == 0) offs[N_NODES] = N_EDGES;
    gridg.sync();

    // ---- phase 3: MFMA edge MLP (verified r8 body, persistent waves) ----
    {
        const int w   = t >> 6;
        const int l   = t & 63;
        const int m16 = l & 15;
        const int q   = l >> 4;
        const unsigned short* w1b = (const unsigned short*)(ws + W1BF_OFF);
        const unsigned short* w2b = (const unsigned short*)(ws + W2BF_OFF);
        const float* b1 = (const float*)(ws + NB1_OFF);
        const float* b2 = (const float*)(ws + NB2_OFF);

        bf16x8 w1f[4][2], w2f[2][2];
#pragma unroll
        for (int ti = 0; ti < 4; ++ti)
#pragma unroll
            for (int c = 0; c < 2; ++c)
                w1f[ti][c] = *(const bf16x8*)(w1b + ((ti * 16 + m16) * 64 + c * 32 + q * 8));
#pragma unroll
        for (int ti = 0; ti < 2; ++ti)
#pragma unroll
            for (int c = 0; c < 2; ++c)
                w2f[ti][c] = *(const bf16x8*)(w2b + ((ti * 16 + m16) * 64 + c * 32 + q * 8));

        const float b1v[4] = { b1[m16], b1[16 + m16], b1[32 + m16], b1[48 + m16] };
        const float b2v[2] = { b2[m16], b2[16 + m16] };
        const int mrow = l >> 2;
        const int sub  = l & 3;

        auto loadA = [&](int eb_, int g, int src, bf16x8& a0, bf16x8& a1) {
            const int e = eb_ + g * 16 + m16;
            if (isbf) {
                const unsigned short* x  = (const unsigned short*)xq;
                const unsigned short* ea = (const unsigned short*)eaq;
                a0 = *(const bf16x8*)(x + (size_t)src * D_NODE + q * 8);
                a1 = *(const bf16x8*)(ea + (size_t)e * D_EDGE + (q & 1) * 8);
            } else {
                const float* x  = (const float*)xq;
                const float* ea = (const float*)eaq;
                const float4* xp = (const float4*)(x + (size_t)src * D_NODE + q * 8);
                a0 = pack_bf8(xp[0], xp[1]);
                const float4* ap = (const float4*)(ea + (size_t)e * D_EDGE + (q & 1) * 8);
                a1 = pack_bf8(ap[0], ap[1]);
            }
        };

        const int nw  = gridDim.x * 4;
        const int wid = blockIdx.x * 4 + w;
        for (int task = wid; task < N_EDGES / 64; task += nw) {
            const int eb = task * 64;
            int srcv[4], posv[4];
#pragma unroll
            for (int g = 0; g < 4; ++g) {
                const int e = eb + g * 16 + m16;
                int dst;
                if (is64) {
                    const long long* ip = (const long long*)idxq;
                    dst = (int)ip[e];
                    srcv[g] = (int)ip[N_EDGES + e];
                } else {
                    const int* ip = (const int*)idxq;
                    dst = ip[e];
                    srcv[g] = ip[N_EDGES + e];
                }
                posv[g] = offs[dst] + rankb[e];
            }

            bf16x8 A0c, A1c, A0n, A1n;
            loadA(eb, 0, srcv[0], A0c, A1c);
#pragma unroll 1
            for (int g = 0; g < 4; ++g) {
                if (g < 3) loadA(eb, g + 1, srcv[g + 1], A0n, A1n);

#pragma unroll
                for (int ti = 0; ti < 4; ++ti) {
                    f32x4 c;
                    c[0] = c[1] = c[2] = c[3] = b1v[ti];
                    c = __builtin_amdgcn_mfma_f32_16x16x32_bf16(A0c, w1f[ti][0], c, 0, 0, 0);
                    c = __builtin_amdgcn_mfma_f32_16x16x32_bf16(A1c, w1f[ti][1], c, 0, 0, 0);
                    unsigned int u0 = pk_bf2(fmaxf(c[0], 0.0f), fmaxf(c[1], 0.0f));
                    unsigned int u1 = pk_bf2(fmaxf(c[2], 0.0f), fmaxf(c[3], 0.0f));
                    hbuf[w][q * 4 + 0][ti * 16 + m16] = (unsigned short)u0;
                    hbuf[w][q * 4 + 1][ti * 16 + m16] = (unsigned short)(u0 >> 16);
                    hbuf[w][q * 4 + 2][ti * 16 + m16] = (unsigned short)u1;
                    hbuf[w][q * 4 + 3][ti * 16 + m16] = (unsigned short)(u1 >> 16);
                }

                bf16x8 a20 = *(const bf16x8*)(&hbuf[w][m16][q * 8]);
                bf16x8 a21 = *(const bf16x8*)(&hbuf[w][m16][32 + q * 8]);
#pragma unroll
                for (int ti = 0; ti < 2; ++ti) {
                    f32x4 c;
                    c[0] = c[1] = c[2] = c[3] = b2v[ti];
                    c = __builtin_amdgcn_mfma_f32_16x16x32_bf16(a20, w2f[ti][0], c, 0, 0, 0);
                    c = __builtin_amdgcn_mfma_f32_16x16x32_bf16(a21, w2f[ti][1], c, 0, 0, 0);
                    unsigned int u0 = pk_bf2(c[0], c[1]);
                    unsigned int u1 = pk_bf2(c[2], c[3]);
                    hbuf[w][q * 4 + 0][ti * 16 + m16] = (unsigned short)u0;
                    hbuf[w][q * 4 + 1][ti * 16 + m16] = (unsigned short)(u0 >> 16);
                    hbuf[w][q * 4 + 2][ti * 16 + m16] = (unsigned short)u1;
                    hbuf[w][q * 4 + 3][ti * 16 + m16] = (unsigned short)(u1 >> 16);
                }

                const int posm = __shfl(posv[g], mrow, 64);
                uint4 rowv = *(const uint4*)(&hbuf[w][mrow][sub * 8]);
                *(uint4*)(msg + (size_t)posm * D_OUT + sub * 8) = rowv;

                A0c = A0n; A1c = A1n;
            }
        }
    }
    gridg.sync();

    // ---- phase 4: reduce (r7's 16-lane-per-node, u32 loads) ----
    for (int ii = gtid; ii < N_NODES * 16; ii += gthreads) {
        const int node = ii >> 4;
        const int c2 = ii & 15;
        const int lo = offs[node], hi = offs[node + 1];
        float s0 = 0.0f, s1 = 0.0f;
        const unsigned int* p = (const unsigned int*)msg + (size_t)lo * 16 + c2;
        int k = lo;
        for (; k + 1 < hi; k += 2) {
            unsigned int a = p[0], b = p[16];
            s0 += __uint_as_float(a << 16) + __uint_as_float(b << 16);
            s1 += __uint_as_float(a & 0xFFFF0000u) + __uint_as_float(b & 0xFFFF0000u);
            p += 32;
        }
        if (k < hi) {
            unsigned int a = p[0];
            s0 += __uint_as_float(a << 16);
            s1 += __uint_as_float(a & 0xFFFF0000u);
        }
        if (isbf) {
            ((unsigned int*)out)[(size_t)node * 16 + c2] = pk_bf2(s0, s1);
        } else {
            float2 v; v.x = s0; v.y = s1;
            ((float2*)out)[(size_t)node * 16 + c2] = v;
        }
    }
}

// ===========================================================================
// FALLBACK: r8 6-launch pipeline (used only if cooperative launch errors)
// ===========================================================================
__global__ __launch_bounds__(256) void prep_kernel(
        const void* __restrict__ xq, const void* __restrict__ idxq,
        const void* __restrict__ W1q, const void* __restrict__ b1q,
        const void* __restrict__ W2q, const void* __restrict__ b2q,
        char* __restrict__ ws) {
    const int t = threadIdx.x;
    const int i0 = blockIdx.x * 256 + t;
    if (i0 < N_NODES) ((int*)(ws + COUNTS_OFF))[i0] = 0;
    if (blockIdx.x != 0) return;
    __shared__ int s_isbf;
    if (t < 64) {
        unsigned short u = ((const unsigned short*)xq)[t];
        unsigned long long mb = __ballot(((u >> 7) & 0xFF) >= 140);
        int wodd = ((const int*)idxq)[2 * t + 1];
        unsigned long long mi = __ballot(wodd != 0);
        if (t == 0) {
            int* flags = (int*)(ws + NFLAGS_OFF);
            flags[0] = (mb == 0ULL);
            flags[1] = (mi == 0ULL);
            s_isbf = (mb == 0ULL);
        }
    }
    __syncthreads();
    const int isbf = s_isbf;
    float* b1 = (float*)(ws + NB1_OFF);
    float* b2 = (float*)(ws + NB2_OFF);
    unsigned short* w1b = (unsigned short*)(ws + W1BF_OFF);
    unsigned short* w2b = (unsigned short*)(ws + W2BF_OFF);
    if (t < D_HID) b1[t] = ld_f(b1q, t, isbf);
    if (t < D_OUT) b2[t] = ld_f(b2q, t, isbf);
    for (int i = t; i < D_HID * 64; i += 256) {
        int n = i >> 6, k = i & 63;
        float v = (k < 48) ? ld_f(W1q, k * D_HID + n, isbf) : 0.0f;
        w1b[i] = f2bf_rne(v);
    }
    for (int i = t; i < D_OUT * 64; i += 256) {
        int n = i >> 6, k = i & 63;
        w2b[i] = f2bf_rne(ld_f(W2q, k * D_OUT + n, isbf));
    }
}

__global__ __launch_bounds__(256) void hist_kernel(const void* __restrict__ idxq,
                                                   char* __restrict__ ws,
                                                   int* __restrict__ rankb) {
    const int is64 = ((const int*)(ws + NFLAGS_OFF))[1];
    const int e = blockIdx.x * 256 + threadIdx.x;
    int dst;
    if (is64) dst = (int)((const long long*)idxq)[e];
    else      dst = ((const int*)idxq)[e];
    rankb[e] = atomicAdd((int*)(ws + COUNTS_OFF) + dst, 1);
}

__global__ __launch_bounds__(256) void scan_block_kernel(char* __restrict__ ws) {
    __shared__ int s[256];
    const int* counts = (const int*)(ws + COUNTS_OFF);
    int* offs   = (int*)(ws + OFFS_OFF);
    int* blksum = (int*)(ws + BLKSUM_OFF);
    const int t = threadIdx.x;
    const int i = blockIdx.x * 256 + t;
    int v = (i < N_NODES) ? counts[i] : 0;
    s[t] = v;
    __syncthreads();
    for (int d = 1; d < 256; d <<= 1) {
        int a = (t >= d) ? s[t - d] : 0;
        __syncthreads();
        s[t] += a;
        __syncthreads();
    }
    if (i < N_NODES) offs[i] = s[t] - v;
    if (t == 255) blksum[blockIdx.x] = s[255];
}

__global__ __launch_bounds__(256) void scan_add_kernel(char* __restrict__ ws) {
    __shared__ int s[256];
    int* offs = (int*)(ws + OFFS_OFF);
    const int* blksum = (const int*)(ws + BLKSUM_OFF);
    const int t = threadIdx.x;
    const int b = blockIdx.x;
    int acc = 0;
    for (int j = t; j < b; j += 256) acc += blksum[j];
    s[t] = acc;
    __syncthreads();
    for (int d = 128; d > 0; d >>= 1) {
        if (t < d) s[t] += s[t + d];
        __syncthreads();
    }
    const int prefix = s[0];
    const int i = b * 256 + t;
    if (i < N_NODES) offs[i] += prefix;
    if (i == 0) offs[N_NODES] = N_EDGES;
}

__global__ __launch_bounds__(256) void edge_mlp_mfma_kernel(
        const void* __restrict__ xq,
        const void* __restrict__ idxq,
        const void* __restrict__ eaq,
        const char* __restrict__ wsro,
        const int* __restrict__ rankb,
        unsigned short* __restrict__ msg) {
    const int isbf = ((const int*)(wsro + NFLAGS_OFF))[0];
    const int is64 = ((const int*)(wsro + NFLAGS_OFF))[1];
    __shared__ __align__(16) unsigned short hbuf[4][16][72];
    const int w   = threadIdx.x >> 6;
    const int l   = threadIdx.x & 63;
    const int m16 = l & 15;
    const int q   = l >> 4;
    const unsigned short* w1b = (const unsigned short*)(wsro + W1BF_OFF);
    const unsigned short* w2b = (const unsigned short*)(wsro + W2BF_OFF);
    const float* b1 = (const float*)(wsro + NB1_OFF);
    const float* b2 = (const float*)(wsro + NB2_OFF);
    const int* offs = (const int*)(wsro + OFFS_OFF);
    bf16x8 w1f[4][2], w2f[2][2];
#pragma unroll
    for (int ti = 0; ti < 4; ++ti)
#pragma unroll
        for (int c = 0; c < 2; ++c)
            w1f[ti][c] = *(const bf16x8*)(w1b + ((ti * 16 + m16) * 64 + c * 32 + q * 8));
#pragma unroll
    for (int ti = 0; ti < 2; ++ti)
#pragma unroll
        for (int c = 0; c < 2; ++c)
            w2f[ti][c] = *(const bf16x8*)(w2b + ((ti * 16 + m16) * 64 + c * 32 + q * 8));
    const int eb = blockIdx.x * 256 + w * 64;
    int srcv[4], posv[4];
#pragma unroll
    for (int g = 0; g < 4; ++g) {
        const int e = eb + g * 16 + m16;
        int dst;
        if (is64) {
            const long long* ip = (const long long*)idxq;
            dst = (int)ip[e];
            srcv[g] = (int)ip[N_EDGES + e];
        } else {
            const int* ip = (const int*)idxq;
            dst = ip[e];
            srcv[g] = ip[N_EDGES + e];
        }
        posv[g] = offs[dst] + rankb[e];
    }
    const float b1v[4] = { b1[m16], b1[16 + m16], b1[32 + m16], b1[48 + m16] };
    const float b2v[2] = { b2[m16], b2[16 + m16] };
    const int mrow = l >> 2;
    const int sub  = l & 3;
    auto loadA = [&](int g, bf16x8& a0, bf16x8& a1) {
        const int e = eb + g * 16 + m16;
        if (isbf) {
            const unsigned short* x  = (const unsigned short*)xq;
            const unsigned short* ea = (const unsigned short*)eaq;
            a0 = *(const bf16x8*)(x + (size_t)srcv[g] * D_NODE + q * 8);
            a1 = *(const bf16x8*)(ea + (size_t)e * D_EDGE + (q & 1) * 8);
        } else {
            const float* x  = (const float*)xq;
            const float* ea = (const float*)eaq;
            const float4* xp = (const float4*)(x + (size_t)srcv[g] * D_NODE + q * 8);
            a0 = pack_bf8(xp[0], xp[1]);
            const float4* ap = (const float4*)(ea + (size_t)e * D_EDGE + (q & 1) * 8);
            a1 = pack_bf8(ap[0], ap[1]);
        }
    };
    bf16x8 A0c, A1c, A0n, A1n;
    loadA(0, A0c, A1c);
#pragma unroll 1
    for (int g = 0; g < 4; ++g) {
        if (g < 3) loadA(g + 1, A0n, A1n);
#pragma unroll
        for (int ti = 0; ti < 4; ++ti) {
            f32x4 c;
            c[0] = c[1] = c[2] = c[3] = b1v[ti];
            c = __builtin_amdgcn_mfma_f32_16x16x32_bf16(A0c, w1f[ti][0], c, 0, 0, 0);
            c = __builtin_amdgcn_mfma_f32_16x16x32_bf16(A1c, w1f[ti][1], c, 0, 0, 0);
            unsigned int u0 = pk_bf2(fmaxf(c[0], 0.0f), fmaxf(c[1], 0.0f));
            unsigned int u1 = pk_bf2(fmaxf(c[2], 0.0f), fmaxf(c[3], 0.0f));
            hbuf[w][q * 4 + 0][ti * 16 + m16] = (unsigned short)u0;
            hbuf[w][q * 4 + 1][ti * 16 + m16] = (unsigned short)(u0 >> 16);
            hbuf[w][q * 4 + 2][ti * 16 + m16] = (unsigned short)u1;
            hbuf[w][q * 4 + 3][ti * 16 + m16] = (unsigned short)(u1 >> 16);
        }
        bf16x8 a20 = *(const bf16x8*)(&hbuf[w][m16][q * 8]);
        bf16x8 a21 = *(const bf16x8*)(&hbuf[w][m16][32 + q * 8]);
#pragma unroll
        for (int ti = 0; ti < 2; ++ti) {
            f32x4 c;
            c[0] = c[1] = c[2] = c[3] = b2v[ti];
            c = __builtin_amdgcn_mfma_f32_16x16x32_bf16(a20, w2f[ti][0], c, 0, 0, 0);
            c = __builtin_amdgcn_mfma_f32_16x16x32_bf16(a21, w2f[ti][1], c, 0, 0, 0);
            unsigned int u0 = pk_bf2(c[0], c[1]);
            unsigned int u1 = pk_bf2(c[2], c[3]);
            hbuf[w][q * 4 + 0][ti * 16 + m16] = (unsigned short)u0;
            hbuf[w][q * 4 + 1][ti * 16 + m16] = (unsigned short)(u0 >> 16);
            hbuf[w][q * 4 + 2][ti * 16 + m16] = (unsigned short)u1;
            hbuf[w][q * 4 + 3][ti * 16 + m16] = (unsigned short)(u1 >> 16);
        }
        const int posm = __shfl(posv[g], mrow, 64);
        uint4 rowv = *(const uint4*)(&hbuf[w][mrow][sub * 8]);
        *(uint4*)(msg + (size_t)posm * D_OUT + sub * 8) = rowv;
        A0c = A0n; A1c = A1n;
    }
}

__global__ __launch_bounds__(256) void reduce_kernel(
        const char* __restrict__ wsro, const unsigned short* __restrict__ msg,
        void* __restrict__ out) {
    const int isbf = ((const int*)(wsro + NFLAGS_OFF))[0];
    const int* offs = (const int*)(wsro + OFFS_OFF);
    const int t = blockIdx.x * 256 + threadIdx.x;
    const int node = t >> 4;
    if (node >= N_NODES) return;
    const int c2 = t & 15;
    const int lo = offs[node], hi = offs[node + 1];
    float s0 = 0.0f, s1 = 0.0f;
    const unsigned int* p = (const unsigned int*)msg + (size_t)lo * 16 + c2;
    int k = lo;
    for (; k + 1 < hi; k += 2) {
        unsigned int a = p[0], b = p[16];
        s0 += __uint_as_float(a << 16) + __uint_as_float(b << 16);
        s1 += __uint_as_float(a & 0xFFFF0000u) + __uint_as_float(b & 0xFFFF0000u);
        p += 32;
    }
    if (k < hi) {
        unsigned int a = p[0];
        s0 += __uint_as_float(a << 16);
        s1 += __uint_as_float(a & 0xFFFF0000u);
    }
    if (isbf) {
        ((unsigned int*)out)[(size_t)node * 16 + c2] = pk_bf2(s0, s1);
    } else {
        float2 v; v.x = s0; v.y = s1;
        ((float2*)out)[(size_t)node * 16 + c2] = v;
    }
}

extern "C" void kernel_launch(void* const* d_in, const int* in_sizes, int n_in,
                              void* d_out, int out_size, void* d_ws, size_t ws_size,
                              hipStream_t stream) {
    const void* x   = d_in[0];
    const void* idx = d_in[1];
    const void* ea  = d_in[2];
    const void* W1  = d_in[3];
    const void* b1  = d_in[4];
    const void* W2  = d_in[5];
    const void* b2  = d_in[6];
    char* ws = (char*)d_ws;

    // ---- preferred: single cooperative launch ----
    int maxB = 0;
    hipError_t oe = hipOccupancyMaxActiveBlocksPerMultiprocessor(&maxB, mega_kernel, 256, 0);
    if (oe == hipSuccess && maxB >= 1) {
        int nb = maxB;
        if (nb > 8) nb = 8;
        int grid = nb * 256;          // 256 CUs on MI355X; co-resident by construction
        void* outp = d_out;
        void* args[] = { (void*)&x, (void*)&idx, (void*)&ea,
                         (void*)&W1, (void*)&b1, (void*)&W2, (void*)&b2,
                         (void*)&ws, (void*)&outp };
        hipError_t le = hipLaunchCooperativeKernel((void*)mega_kernel,
                                                   dim3(grid), dim3(256),
                                                   args, 0, stream);
        if (le == hipSuccess) return;
    }

    // ---- fallback: r8 6-launch pipeline ----
    hipLaunchKernelGGL(prep_kernel, dim3(SCAN_NB), dim3(256), 0, stream,
                       x, idx, W1, b1, W2, b2, ws);
    hipLaunchKernelGGL(hist_kernel, dim3(N_EDGES / 256), dim3(256), 0, stream,
                       idx, ws, (int*)(ws + RANK_OFF));
    hipLaunchKernelGGL(scan_block_kernel, dim3(SCAN_NB), dim3(256), 0, stream, ws);
    hipLaunchKernelGGL(scan_add_kernel,   dim3(SCAN_NB), dim3(256), 0, stream, ws);
    hipLaunchKernelGGL(edge_mlp_mfma_kernel, dim3(N_EDGES / 256), dim3(256), 0, stream,
                       x, idx, ea, (const char*)ws,
                       (const int*)(ws + RANK_OFF), (unsigned short*)(ws + MSG_OFF));
    hipLaunchKernelGGL(reduce_kernel, dim3((N_NODES * 16 + 255) / 256), dim3(256), 0, stream,
                       (const char*)ws, (const unsigned short*)(ws + MSG_OFF), d_out);
}